// Round 9
// baseline (112.537 us; speedup 1.0000x reference)
//
#include <hip/hip_runtime.h>

typedef short bf16x8 __attribute__((ext_vector_type(8)));
typedef short bf16x4 __attribute__((ext_vector_type(4)));
typedef float floatx4 __attribute__((ext_vector_type(4)));

// fp32 -> bf16 round-to-nearest-even (finite inputs)
static __device__ __forceinline__ unsigned short f2bf(float f) {
  unsigned int x = __float_as_uint(f);
  x += 0x7fffu + ((x >> 16) & 1u);
  return (unsigned short)(x >> 16);
}

// KP (emb only, 64 blocks): emb -> eb bf16 + hn[k] = 0.5*||e_k||^2 ; block 0 zeroes loss.
__global__ __launch_bounds__(256) void k_prep(const float* __restrict__ emb,
                                              unsigned short* __restrict__ eb,
                                              float* __restrict__ hn,
                                              float* __restrict__ loss) {
  const int t = threadIdx.x, bid = blockIdx.x;
  if (bid == 0 && t == 0) *loss = 0.f;       // k_fullk (later dispatch) is the only reader/adder
  const int w = t >> 6, lane = t & 63;
  const int kb = (bid << 4) + (w << 2);
  for (int jj = 0; jj < 4; ++jj) {
    const int k = kb + jj;
    const float* er = emb + (k << 8);
    unsigned short* eo = eb + (k << 8);
    float ss = 0.f;
    for (int j = 0; j < 4; ++j) {
      const float v = er[j * 64 + lane];
      ss += v * v;
      eo[j * 64 + lane] = f2bf(v);
    }
    for (int off = 32; off >= 1; off >>= 1) ss += __shfl_xor(ss, off, 64);
    if (lane == 0) hn[k] = 0.5f * ss;
  }
}

// KB9: 512 blocks x 256 thr x 64 rows, FULL 1024 codes/block, fused output.
// R8 post-mortem: envelope identity dur = 43us fill + sum(kernels) + ~3us held for 4 rounds,
// then broke -- profiled k_fullk <42us (warm: rocprof replays) but dur_us barely moved.
// Hypothesis: the TIMED run is cache-COLD (the 268MB poison fill sweeps L2/L3), and the
// cold cost concentrates in phase-0's 33.5MB x read, whose cold-run time is set by MLP
// (outstanding misses at ~900cyc HBM latency), not BW. R8's stage A consumed each float4
// immediately (ss + LDS write) -> compiler keeps few loads in flight.
// FIX: stage A issues TWO BATCHES of 8 float4 loads back-to-back into registers BEFORE any
// consumption (>=8 concurrent 1KB misses/wave -> HBM-saturating even fully cold).
// ss accumulation order over p unchanged (0..15) -> xn2 bit-identical, absmax unchanged.
// Also: s_setprio(1/0) around the MFMA cluster (T5; waves are barrier-free/independent --
// the regime where setprio measured +4-7%). Everything else identical to R8.
__global__ __launch_bounds__(256, 2) void k_fullk(const float* __restrict__ x,
                                                  const unsigned short* __restrict__ eb,
                                                  const float* __restrict__ hn,
                                                  const float* __restrict__ emb,
                                                  float* __restrict__ out,
                                                  float* __restrict__ loss) {
  // LDS map (bytes):
  //   [0, 33792)        tile2[64*264] shorts == es0 (E dbuf 0); sel f32 overlays at tail
  //   [33792, 67584)    tmp[256*64] shorts (32768 B) == es1 (E dbuf 1)
  //   [67584, 71680)    xred2[4][256] f32 (prologue) == hn_l[1024] f32 (main loop)
  //   [71680, 72704)    bvs[4][64] f32
  //   [72704, 73728)    bis[4][64] i32
  //   [73728, 73984)    idx_l[64] i32
  //   [73984, 74240)    xn2_l[64] f32
  __shared__ __align__(16) char smem[74240];
  unsigned short* es0 = (unsigned short*)smem;
  unsigned short* es1 = (unsigned short*)(smem + 33792);
  unsigned short* tile2 = es0;
  unsigned short* tmp   = es1;
  float* sel   = (float*)smem;
  float* hn_l  = (float*)(smem + 67584);
  float* xred2 = (float*)(smem + 67584);
  float* bvs   = (float*)(smem + 71680);
  int*   bis   = (int*)(smem + 72704);
  int*   idx_l = (int*)(smem + 73728);
  float* xn2_l = (float*)(smem + 73984);

  const int t = threadIdx.x;
  const int cq = t >> 6, lane = t & 63;        // wave = code-quarter
  const int r16 = lane & 15, quad = lane >> 4;
  const int n0 = blockIdx.x << 6;              // 64 rows/block
  const int b = n0 >> 10, hw0 = n0 & 1023;

  // staging geometry (wave-private: wave w stages es rows 16w..16w+15 == rows wave cq=w reads)
  const int g = t >> 5, c32 = (t & 31) << 3;

  // ---- step 1: issue E-tile0 loads EARLY (latency hides under the x read) ----
  bf16x8 pf0[8];
#pragma unroll
  for (int i = 0; i < 8; ++i) {
    const int r = (g << 3) + i;
    const int code = ((r >> 4) << 8) + (r & 15);                    // kt=0
    pf0[i] = *(const bf16x8*)(eb + ((size_t)code << 8) + c32);
  }

  // ---- stage A: x float4 loads (two 8-deep batches: MLP even when HBM-cold) ----
  {
    const int hwq = t & 15, cidx = t >> 4;
    const float* xpb = x + ((size_t)b << 18) + hw0 + (hwq << 2);
    float4 vv[8], vw[8];
#pragma unroll
    for (int p = 0; p < 8; ++p)
      vv[p] = *(const float4*)(xpb + ((size_t)((p << 4) + cidx) << 10));
#pragma unroll
    for (int p = 0; p < 8; ++p)
      vw[p] = *(const float4*)(xpb + ((size_t)(((p + 8) << 4) + cidx) << 10));
    float ss0 = 0.f, ss1 = 0.f, ss2 = 0.f, ss3 = 0.f;
#pragma unroll
    for (int p = 0; p < 8; ++p) {              // p = 0..7 (order matches R8)
      const int c = (p << 4) + cidx;
      const float4 v = vv[p];
      ss0 += v.x * v.x; ss1 += v.y * v.y; ss2 += v.z * v.z; ss3 += v.w * v.w;
      bf16x4 u;
      u[0] = (short)f2bf(v.x); u[1] = (short)f2bf(v.y);
      u[2] = (short)f2bf(v.z); u[3] = (short)f2bf(v.w);
      *(bf16x4*)(&tmp[(c << 6) + (hwq << 2)]) = u;                  // tmp[c*64 + hw]
    }
#pragma unroll
    for (int p = 0; p < 8; ++p) {              // p = 8..15
      const int c = ((p + 8) << 4) + cidx;
      const float4 v = vw[p];
      ss0 += v.x * v.x; ss1 += v.y * v.y; ss2 += v.z * v.z; ss3 += v.w * v.w;
      bf16x4 u;
      u[0] = (short)f2bf(v.x); u[1] = (short)f2bf(v.y);
      u[2] = (short)f2bf(v.z); u[3] = (short)f2bf(v.w);
      *(bf16x4*)(&tmp[(c << 6) + (hwq << 2)]) = u;
    }
    xred2[t] = ss0; xred2[256 + t] = ss1; xred2[512 + t] = ss2; xred2[768 + t] = ss3;
  }
  __syncthreads();                             // tmp + xred2 complete

  // ---- stage B: tmp[c][hw] -> tile2[hw][c] (b16 reads are 2-lanes/dword: conflict-free) ----
  {
    const int row = t & 63, wv = t >> 6;
    for (int s = 0; s < 8; ++s) {
      const int c8 = wv + (s << 2);
      bf16x8 u;
#pragma unroll
      for (int k = 0; k < 8; ++k) u[k] = (short)tmp[(((c8 << 3) + k) << 6) + row];
      *(bf16x8*)(&tile2[row * 264 + (c8 << 3)]) = u;
    }
  }
  // xn2 reduce (wave 0; xred2 still live -- hn_l overwrite happens after barrier below)
  if (t < 64) {
    float s = 0.f;
    for (int ci2 = 0; ci2 < 16; ++ci2)
      s += xred2[(t & 3) * 256 + (ci2 << 4) + (t >> 2)];
    xn2_l[t] = s;
  }
  __syncthreads();                             // tile2 complete; xred2 consumed

  // A fragments from tile2: rows rg*16 + r16, c = quad*8 + ci*32 (bit-identical to R8)
  bf16x8 a[4][8];
  for (int rg = 0; rg < 4; ++rg) {
    const unsigned short* tr = tile2 + ((rg << 4) + r16) * 264 + (quad << 3);
#pragma unroll
    for (int ci = 0; ci < 8; ++ci) a[rg][ci] = *(const bf16x8*)(tr + (ci << 5));
  }
  // hn quarter, WAVE-PRIVATE (overlays xred2 -- dead now)
  for (int i = 0; i < 4; ++i)
    hn_l[(cq << 8) + (i << 6) + lane] = hn[(cq << 8) + (i << 6) + lane];
  __syncthreads();                             // tile2 consumed by all; es0 free

  // ---- E prologue: write preloaded tile0 -> es0; issue tile1 prefetch ----
  bf16x8 pf[8];
#pragma unroll
  for (int i = 0; i < 8; ++i) *(bf16x8*)(&es0[((g << 3) + i) * 264 + c32]) = pf0[i];
#pragma unroll
  for (int i = 0; i < 8; ++i) {
    const int r = (g << 3) + i;
    const int code = ((r >> 4) << 8) + 16 + (r & 15);               // kt=1
    pf[i] = *(const bf16x8*)(eb + ((size_t)code << 8) + c32);
  }

  float bv[4][4]; int bi[4][4];
  for (int rg = 0; rg < 4; ++rg)
    for (int r = 0; r < 4; ++r) { bv[rg][r] = -3.4e38f; bi[rg][r] = 0; }

  // ---- main loop: barrier-free, wave-private es double-buffer (R5 form) ----
  int cur = 0;
  for (int kt = 0; kt < 16; ++kt) {
    unsigned short* esc = cur ? es1 : es0;
    unsigned short* esn = cur ? es0 : es1;
    if (kt < 15)                               // write tile kt+1 (pf) into the other buffer
#pragma unroll
      for (int i = 0; i < 8; ++i) *(bf16x8*)(&esn[((g << 3) + i) * 264 + c32]) = pf[i];
    if (kt < 14) {                             // issue prefetch of tile kt+2
#pragma unroll
      for (int i = 0; i < 8; ++i) {
        const int r = (g << 3) + i;
        const int code = ((r >> 4) << 8) + ((kt + 2) << 4) + (r & 15);
        pf[i] = *(const bf16x8*)(eb + ((size_t)code << 8) + c32);
      }
    }
    // compute: this wave's 16 codes (es rows cq*16 + r16) vs the block's 64 rows
    const unsigned short* esr = &esc[((cq << 4) + r16) * 264 + (quad << 3)];
    floatx4 acc0 = {0.f,0.f,0.f,0.f}, acc1 = {0.f,0.f,0.f,0.f};
    floatx4 acc2 = {0.f,0.f,0.f,0.f}, acc3 = {0.f,0.f,0.f,0.f};
    __builtin_amdgcn_s_setprio(1);             // T5: favor the MFMA cluster (waves unsynced)
#pragma unroll
    for (int ci = 0; ci < 8; ++ci) {
      const bf16x8 bfr = *(const bf16x8*)(esr + (ci << 5));  // 1 read feeds 4 MFMAs
      acc0 = __builtin_amdgcn_mfma_f32_16x16x32_bf16(a[0][ci], bfr, acc0, 0, 0, 0);
      acc1 = __builtin_amdgcn_mfma_f32_16x16x32_bf16(a[1][ci], bfr, acc1, 0, 0, 0);
      acc2 = __builtin_amdgcn_mfma_f32_16x16x32_bf16(a[2][ci], bfr, acc2, 0, 0, 0);
      acc3 = __builtin_amdgcn_mfma_f32_16x16x32_bf16(a[3][ci], bfr, acc3, 0, 0, 0);
    }
    __builtin_amdgcn_s_setprio(0);
    const int kglob = (cq << 8) + (kt << 4) + r16;
    const float h = hn_l[kglob];
#pragma unroll
    for (int r = 0; r < 4; ++r) {              // D: row = quad*4 + r, col(code) = r16
      float v;
      v = acc0[r] - h; if (v > bv[0][r]) { bv[0][r] = v; bi[0][r] = kglob; }
      v = acc1[r] - h; if (v > bv[1][r]) { bv[1][r] = v; bi[1][r] = kglob; }
      v = acc2[r] - h; if (v > bv[2][r]) { bv[2][r] = v; bi[2][r] = kglob; }
      v = acc3[r] - h; if (v > bv[3][r]) { bv[3][r] = v; bi[3][r] = kglob; }
    }
    cur ^= 1;                                  // wave-private flip; no barrier
  }

  // reduce across the 16 code-columns (within each 16-lane group); ties -> lowest index
  for (int off = 8; off >= 1; off >>= 1)
    for (int rg = 0; rg < 4; ++rg)
      for (int r = 0; r < 4; ++r) {
        const float ov = __shfl_xor(bv[rg][r], off, 64);
        const int   oi = __shfl_xor(bi[rg][r], off, 64);
        if (ov > bv[rg][r] || (ov == bv[rg][r] && oi < bi[rg][r])) { bv[rg][r] = ov; bi[rg][r] = oi; }
      }
  if (r16 == 0) {
    for (int rg = 0; rg < 4; ++rg)
      for (int r = 0; r < 4; ++r) {
        const int row = (rg << 4) + (quad << 2) + r;
        bvs[(cq << 6) + row] = bv[rg][r];
        bis[(cq << 6) + row] = bi[rg][r];
      }
  }
  __syncthreads();                             // all quarters' bvs/bis visible

  // merge the 4 code-quarters (ascending q: strict > keeps lowest code on ties) + loss
  if (t < 64) {
    float vm = bvs[t]; int im = bis[t];
    for (int q = 1; q < 4; ++q) {
      const float v = bvs[(q << 6) + t];
      if (v > vm) { vm = v; im = bis[(q << 6) + t]; }
    }
    idx_l[t] = im;
    float lv = xn2_l[t] - 2.f * vm;            // = ||x_n - e_{im}||^2
    for (int off = 32; off >= 1; off >>= 1) lv += __shfl_xor(lv, off, 64);
    if (t == 0) atomicAdd(loss, lv * (1.25f / 8388608.0f));
  }
  __syncthreads();                             // es dead + idx_l ready; sel may overwrite

  // gather winning code rows into LDS (coalesced 256B loads from L2-resident emb)
  for (int i = 0; i < 16; ++i) {
    const int row = (cq << 4) + i;
    const float* er = emb + ((size_t)idx_l[row] << 8);
    for (int j = 0; j < 4; ++j)
      sel[row * 257 + (j << 6) + lane] = er[(j << 6) + lane];
  }
  __syncthreads();
  // write out: float4 along hw (16B/lane), 256B segments per c
  const int hwq = t & 15, cg = t >> 4;
  const size_t base = ((size_t)b << 18);       // b*256*1024
  for (int it = 0; it < 16; ++it) {
    const int c = (it << 4) + cg;
    float4 v;
    v.x = sel[(hwq * 4 + 0) * 257 + c];
    v.y = sel[(hwq * 4 + 1) * 257 + c];
    v.z = sel[(hwq * 4 + 2) * 257 + c];
    v.w = sel[(hwq * 4 + 3) * 257 + c];
    *(float4*)(out + base + ((size_t)c << 10) + hw0 + (hwq << 2)) = v;
  }
}

extern "C" void kernel_launch(void* const* d_in, const int* in_sizes, int n_in,
                              void* d_out, int out_size, void* d_ws, size_t ws_size,
                              hipStream_t stream) {
  const float* x   = (const float*)d_in[0];
  const float* emb = (const float*)d_in[1];
  float* out  = (float*)d_out;
  float* loss = out + 8388608;

  char* ws = (char*)d_ws;
  unsigned short* eb = (unsigned short*)(ws);              // 524,288 B
  float* hn = (float*)(ws + 524288);                       //   4,096 B

  k_prep<<<64, 256, 0, stream>>>(emb, eb, hn, loss);
  k_fullk<<<512, 256, 0, stream>>>(x, eb, hn, emb, out, loss);
}